// Round 1
// baseline (1004.498 us; speedup 1.0000x reference)
//
#include <hip/hip_runtime.h>

#define BATCH  4096
#define TSTEPS 64
#define FDIM   128
#define HDIM   256
#define ODIM   64
#define MROWS  32
#define NBLK   128   // BATCH / MROWS
#define NTHR   512   // 8 waves

typedef __attribute__((ext_vector_type(8))) short  short8;
typedef __attribute__((ext_vector_type(4))) float  floatx4;

#define MFMA(a,b,c) __builtin_amdgcn_mfma_f32_16x16x32_bf16((a),(b),(c),0,0,0)

__device__ __forceinline__ unsigned short f2bf(float f){
  unsigned u = __builtin_bit_cast(unsigned, f);
  u += 0x7FFFu + ((u >> 16) & 1u);           // RTNE
  return (unsigned short)(u >> 16);
}
__device__ __forceinline__ float sigm(float x){
  return __builtin_amdgcn_rcpf(1.f + __expf(-x));
}
__device__ __forceinline__ float tanh_f(float x){
  return 2.f * __builtin_amdgcn_rcpf(1.f + __expf(-2.f * x)) - 1.f;
}

// ---------------- phase 0: fragment + bf16-convert weights into d_ws ----------
// layout: warr[((gf*12 + kf)*64 + lane)*8 + i]
//   gf 0..47 (gate-col frags of 16), kf 0..7 -> w_hh k=32kf, kf 8..11 -> w_ih k=32(kf-8)
//   element = W[16*gf + (lane&15)][32*kf + 8*(lane>>4) + i]   (A-frag layout, row=lane&15)
__global__ void prep_weights(const float* __restrict__ w_ih,
                             const float* __restrict__ w_hh,
                             unsigned short* __restrict__ warr){
  int idx = blockIdx.x * 256 + threadIdx.x;
  if (idx >= 48*12*64) return;
  int gf   = idx / 768;
  int rr   = idx - gf*768;
  int kf   = rr >> 6;
  int lane = rr & 63;
  int lo = lane & 15, hi = lane >> 4;
  const float* src = (kf < 8) ? (w_hh + (size_t)(16*gf + lo)*HDIM + 32*kf     + 8*hi)
                              : (w_ih + (size_t)(16*gf + lo)*FDIM + 32*(kf-8) + 8*hi);
  unsigned short* dst = warr + (size_t)idx * 8;
  #pragma unroll
  for (int i = 0; i < 8; ++i) dst[i] = f2bf(src[i]);
}

// swizzled LDS B-frag loads: byte = row*stride + (kb ^ ((row&7)<<4))
__device__ __forceinline__ short8 ldsH(const unsigned char* sm, int row, int kb){
  return *(const short8*)(sm + row*512 + (kb ^ ((row & 7) << 4)));
}
__device__ __forceinline__ short8 ldsX(const unsigned char* sm, int row, int kb){
  return *(const short8*)(sm + row*256 + (kb ^ ((row & 7) << 4)));
}

__device__ __forceinline__ void stage_x(const float* __restrict__ feat,
                                        unsigned char* sm_x, int row0, int tid, int t){
  // stage features[row0..row0+31, t, :] as swizzled bf16 [32][128]
  #pragma unroll
  for (int i = 0; i < 2; ++i){
    int cid = tid + i*NTHR;        // 0..1023
    int r   = cid >> 5;            // 0..31
    int c4  = cid & 31;            // float4 chunk
    const float4* fp = (const float4*)(feat + (size_t)(row0 + r)*(TSTEPS*FDIM) + (size_t)t*FDIM) + c4;
    float4 v = *fp;
    uint2 pk;
    pk.x = (unsigned)f2bf(v.x) | ((unsigned)f2bf(v.y) << 16);
    pk.y = (unsigned)f2bf(v.z) | ((unsigned)f2bf(v.w) << 16);
    int byte = r*256 + ((c4*8) ^ ((r & 7) << 4));
    *(uint2*)(sm_x + byte) = pk;
  }
}

// ---------------- main fused kernel ----------------
__global__ __launch_bounds__(NTHR, 2)
void gru_fused(const float* __restrict__ feat,
               const unsigned short* __restrict__ warr,
               const float* __restrict__ b_ih, const float* __restrict__ b_hh,
               const float* __restrict__ w_pi, const float* __restrict__ b_pi,
               const float* __restrict__ w_vf, const float* __restrict__ b_vf,
               float* __restrict__ out){
  __shared__ __align__(16) unsigned char sm_h[MROWS*512];  // 16KB bf16 [32][256] swizzled
  __shared__ __align__(16) unsigned char sm_x[MROWS*256];  // 8KB  bf16 [32][128] swizzled

  const int tid  = threadIdx.x;
  const int wv   = tid >> 6;           // wave 0..7 -> owns h-cols [32wv, 32wv+32)
  const int lane = tid & 63;
  const int lo   = lane & 15, hi = lane >> 4;
  const int row0 = blockIdx.x * MROWS;
  const int hc   = wv * 32;

  // bias preload (acc init values); gate col = 16*gf + 4*hi + j
  float brz[4][4], bxn[2][4], bhn[2][4];
  #pragma unroll
  for (int mf = 0; mf < 4; ++mf){
    #pragma unroll
    for (int j = 0; j < 4; ++j){
      int c = (mf < 2) ? (hc + 16*mf + 4*hi + j) : (256 + hc + 16*(mf-2) + 4*hi + j);
      brz[mf][j] = b_ih[c] + b_hh[c];
    }
  }
  #pragma unroll
  for (int mf = 0; mf < 2; ++mf){
    #pragma unroll
    for (int j = 0; j < 4; ++j){
      int c = 512 + hc + 16*mf + 4*hi + j;
      bxn[mf][j] = b_ih[c];
      bhn[mf][j] = b_hh[c];
    }
  }

  const unsigned short* wl = warr + lane*8;
  const int gfr = 2*wv, gfz = 16 + 2*wv, gfn = 32 + 2*wv;

  float hold[2][2][4];   // fp32 h state: [bnf][mfh][j]
  #pragma unroll
  for (int b = 0; b < 2; ++b)
    #pragma unroll
    for (int m = 0; m < 2; ++m)
      #pragma unroll
      for (int j = 0; j < 4; ++j) hold[b][m][j] = 0.f;

  // zero h LDS, stage x[0]
  #pragma unroll
  for (int i = 0; i < 2; ++i) ((int4*)sm_h)[tid + i*NTHR] = make_int4(0,0,0,0);
  stage_x(feat, sm_x, row0, tid, 0);
  __syncthreads();

  for (int t = 0; t < TSTEPS; ++t){
    floatx4 arz[4][2], axn[2][2], ahn[2][2];
    #pragma unroll
    for (int mf = 0; mf < 4; ++mf){
      floatx4 v; v[0]=brz[mf][0]; v[1]=brz[mf][1]; v[2]=brz[mf][2]; v[3]=brz[mf][3];
      arz[mf][0] = v; arz[mf][1] = v;
    }
    #pragma unroll
    for (int mf = 0; mf < 2; ++mf){
      floatx4 vx; vx[0]=bxn[mf][0]; vx[1]=bxn[mf][1]; vx[2]=bxn[mf][2]; vx[3]=bxn[mf][3];
      axn[mf][0] = vx; axn[mf][1] = vx;
      floatx4 vh; vh[0]=bhn[mf][0]; vh[1]=bhn[mf][1]; vh[2]=bhn[mf][2]; vh[3]=bhn[mf][3];
      ahn[mf][0] = vh; ahn[mf][1] = vh;
    }

    // h-part: K = 256 (8 kf)
    #pragma unroll
    for (int kf = 0; kf < 8; ++kf){
      short8 b0 = ldsH(sm_h, lo,      kf*64 + hi*16);
      short8 b1 = ldsH(sm_h, 16 + lo, kf*64 + hi*16);
      const int o = kf*512;
      short8 a0 = *(const short8*)(wl + gfr*6144     + o);
      short8 a1 = *(const short8*)(wl + (gfr+1)*6144 + o);
      short8 a2 = *(const short8*)(wl + gfz*6144     + o);
      short8 a3 = *(const short8*)(wl + (gfz+1)*6144 + o);
      short8 a4 = *(const short8*)(wl + gfn*6144     + o);
      short8 a5 = *(const short8*)(wl + (gfn+1)*6144 + o);
      arz[0][0] = MFMA(a0,b0,arz[0][0]); arz[0][1] = MFMA(a0,b1,arz[0][1]);
      arz[1][0] = MFMA(a1,b0,arz[1][0]); arz[1][1] = MFMA(a1,b1,arz[1][1]);
      arz[2][0] = MFMA(a2,b0,arz[2][0]); arz[2][1] = MFMA(a2,b1,arz[2][1]);
      arz[3][0] = MFMA(a3,b0,arz[3][0]); arz[3][1] = MFMA(a3,b1,arz[3][1]);
      ahn[0][0] = MFMA(a4,b0,ahn[0][0]); ahn[0][1] = MFMA(a4,b1,ahn[0][1]);
      ahn[1][0] = MFMA(a5,b0,ahn[1][0]); ahn[1][1] = MFMA(a5,b1,ahn[1][1]);
    }
    // x-part: K = 128 (4 kf)
    #pragma unroll
    for (int kx = 0; kx < 4; ++kx){
      short8 b0 = ldsX(sm_x, lo,      kx*64 + hi*16);
      short8 b1 = ldsX(sm_x, 16 + lo, kx*64 + hi*16);
      const int o = (8 + kx)*512;
      short8 a0 = *(const short8*)(wl + gfr*6144     + o);
      short8 a1 = *(const short8*)(wl + (gfr+1)*6144 + o);
      short8 a2 = *(const short8*)(wl + gfz*6144     + o);
      short8 a3 = *(const short8*)(wl + (gfz+1)*6144 + o);
      short8 a4 = *(const short8*)(wl + gfn*6144     + o);
      short8 a5 = *(const short8*)(wl + (gfn+1)*6144 + o);
      arz[0][0] = MFMA(a0,b0,arz[0][0]); arz[0][1] = MFMA(a0,b1,arz[0][1]);
      arz[1][0] = MFMA(a1,b0,arz[1][0]); arz[1][1] = MFMA(a1,b1,arz[1][1]);
      arz[2][0] = MFMA(a2,b0,arz[2][0]); arz[2][1] = MFMA(a2,b1,arz[2][1]);
      arz[3][0] = MFMA(a3,b0,arz[3][0]); arz[3][1] = MFMA(a3,b1,arz[3][1]);
      axn[0][0] = MFMA(a4,b0,axn[0][0]); axn[0][1] = MFMA(a4,b1,axn[0][1]);
      axn[1][0] = MFMA(a5,b0,axn[1][0]); axn[1][1] = MFMA(a5,b1,axn[1][1]);
    }
    __syncthreads();   // all reads of sm_h / sm_x done

    // lane-local gate math + h update; write new h (bf16, swizzled, 8B packed)
    #pragma unroll
    for (int b = 0; b < 2; ++b){
      int rowb = 16*b + lo;
      #pragma unroll
      for (int m = 0; m < 2; ++m){
        unsigned q[4];
        #pragma unroll
        for (int j = 0; j < 4; ++j){
          float r  = sigm(arz[m][b][j]);
          float z  = sigm(arz[2+m][b][j]);
          float n  = tanh_f(axn[m][b][j] + r*ahn[m][b][j]);
          float hv = (1.f - z)*n + z*hold[b][m][j];
          hold[b][m][j] = hv;
          q[j] = f2bf(hv);
        }
        uint2 pk; pk.x = q[0] | (q[1] << 16); pk.y = q[2] | (q[3] << 16);
        int cb   = (hc + 16*m + 4*hi) * 2;
        int byte = rowb*512 + (cb ^ ((rowb & 7) << 4));
        *(uint2*)(sm_h + byte) = pk;
      }
    }
    if (t + 1 < TSTEPS) stage_x(feat, sm_x, row0, tid, t + 1);
    __syncthreads();   // h[t+1], x[t+1] visible
  }

  // ---- heads: out = leaky(h_last); write bf16 to sm_h; then pi/vf = leaky(out@W^T+b)
  #pragma unroll
  for (int b = 0; b < 2; ++b){
    int rowb = 16*b + lo;
    #pragma unroll
    for (int m = 0; m < 2; ++m){
      unsigned q[4];
      #pragma unroll
      for (int j = 0; j < 4; ++j){
        float v = hold[b][m][j];
        v = (v >= 0.f) ? v : 0.01f*v;
        q[j] = f2bf(v);
      }
      uint2 pk; pk.x = q[0] | (q[1] << 16); pk.y = q[2] | (q[3] << 16);
      int cb   = (hc + 16*m + 4*hi) * 2;
      int byte = rowb*512 + (cb ^ ((rowb & 7) << 4));
      *(uint2*)(sm_h + byte) = pk;
    }
  }
  __syncthreads();

  const int head = wv >> 2;            // 0 = pi, 1 = vf
  const int mfo  = wv & 3;             // outdim frag
  const float* wh = head ? w_vf : w_pi;
  const float* bh = head ? b_vf : b_pi;
  floatx4 acc0 = {0.f,0.f,0.f,0.f}, acc1 = {0.f,0.f,0.f,0.f};
  #pragma unroll
  for (int kf = 0; kf < 8; ++kf){
    short8 b0 = ldsH(sm_h, lo,      kf*64 + hi*16);
    short8 b1 = ldsH(sm_h, 16 + lo, kf*64 + hi*16);
    const float* ap = wh + (size_t)(16*mfo + lo)*HDIM + 32*kf + 8*hi;
    float4 av0 = *(const float4*)ap;
    float4 av1 = *(const float4*)(ap + 4);
    short8 a;
    a[0]=(short)f2bf(av0.x); a[1]=(short)f2bf(av0.y); a[2]=(short)f2bf(av0.z); a[3]=(short)f2bf(av0.w);
    a[4]=(short)f2bf(av1.x); a[5]=(short)f2bf(av1.y); a[6]=(short)f2bf(av1.z); a[7]=(short)f2bf(av1.w);
    acc0 = MFMA(a, b0, acc0);
    acc1 = MFMA(a, b1, acc1);
  }
  const size_t outoff = (size_t)head * ((size_t)BATCH * ODIM);
  #pragma unroll
  for (int b = 0; b < 2; ++b){
    floatx4 ac = b ? acc1 : acc0;
    int grow = row0 + 16*b + lo;
    #pragma unroll
    for (int j = 0; j < 4; ++j){
      int od = 16*mfo + 4*hi + j;
      float v = ac[j] + bh[od];
      v = (v >= 0.f) ? v : 0.01f*v;
      out[outoff + (size_t)grow*ODIM + od] = v;
    }
  }
}

extern "C" void kernel_launch(void* const* d_in, const int* in_sizes, int n_in,
                              void* d_out, int out_size, void* d_ws, size_t ws_size,
                              hipStream_t stream){
  const float* feat = (const float*)d_in[0];
  const float* w_ih = (const float*)d_in[1];
  const float* w_hh = (const float*)d_in[2];
  const float* b_ih = (const float*)d_in[3];
  const float* b_hh = (const float*)d_in[4];
  const float* w_pi = (const float*)d_in[5];
  const float* b_pi = (const float*)d_in[6];
  const float* w_vf = (const float*)d_in[7];
  const float* b_vf = (const float*)d_in[8];
  unsigned short* warr = (unsigned short*)d_ws;   // 48*12*64*8 bf16 = 589824 B

  prep_weights<<<144, 256, 0, stream>>>(w_ih, w_hh, warr);
  gru_fused<<<NBLK, NTHR, 0, stream>>>(feat, warr, b_ih, b_hh,
                                       w_pi, b_pi, w_vf, b_vf, (float*)d_out);
}

// Round 2
// 897.946 us; speedup vs baseline: 1.1187x; 1.1187x over previous
//
#include <hip/hip_runtime.h>

#define BATCH  4096
#define TSTEPS 64
#define FDIM   128
#define HDIM   256
#define ODIM   64
#define MROWS  32
#define NBLK   128   // BATCH / MROWS
#define NTHR   512   // 8 waves

typedef __attribute__((ext_vector_type(8))) short  short8;
typedef __attribute__((ext_vector_type(4))) float  floatx4;

#define MFMA(a,b,c) __builtin_amdgcn_mfma_f32_16x16x32_bf16((a),(b),(c),0,0,0)

__device__ __forceinline__ unsigned short f2bf(float f){
  unsigned u = __builtin_bit_cast(unsigned, f);
  u += 0x7FFFu + ((u >> 16) & 1u);           // RTNE
  return (unsigned short)(u >> 16);
}
__device__ __forceinline__ float sigm(float x){
  return __builtin_amdgcn_rcpf(1.f + __expf(-x));
}
__device__ __forceinline__ float tanh_f(float x){
  return 2.f * __builtin_amdgcn_rcpf(1.f + __expf(-2.f * x)) - 1.f;
}

// ---------------- phase 0: fragment + bf16-convert weights into d_ws ----------
// layout: warr[((gf*12 + kf)*64 + lane)*8 + i]
//   gf 0..47 (gate-col frags of 16), kf 0..7 -> w_hh k=32kf, kf 8..11 -> w_ih k=32(kf-8)
//   element = W[16*gf + (lane&15)][32*kf + 8*(lane>>4) + i]   (A-frag layout, row=lane&15)
__global__ void prep_weights(const float* __restrict__ w_ih,
                             const float* __restrict__ w_hh,
                             unsigned short* __restrict__ warr){
  int idx = blockIdx.x * 256 + threadIdx.x;
  if (idx >= 48*12*64) return;
  int gf   = idx / 768;
  int rr   = idx - gf*768;
  int kf   = rr >> 6;
  int lane = rr & 63;
  int lo = lane & 15, hi = lane >> 4;
  const float* src = (kf < 8) ? (w_hh + (size_t)(16*gf + lo)*HDIM + 32*kf     + 8*hi)
                              : (w_ih + (size_t)(16*gf + lo)*FDIM + 32*(kf-8) + 8*hi);
  unsigned short* dst = warr + (size_t)idx * 8;
  #pragma unroll
  for (int i = 0; i < 8; ++i) dst[i] = f2bf(src[i]);
}

// swizzled LDS B-frag loads: byte = row*stride + (kb ^ ((row&7)<<4))
__device__ __forceinline__ short8 ldsH(const unsigned char* sm, int row, int kb){
  return *(const short8*)(sm + row*512 + (kb ^ ((row & 7) << 4)));
}
__device__ __forceinline__ short8 ldsX(const unsigned char* sm, int row, int kb){
  return *(const short8*)(sm + row*256 + (kb ^ ((row & 7) << 4)));
}

__device__ __forceinline__ void stage_x(const float* __restrict__ feat,
                                        unsigned char* sm_x, int row0, int tid, int t){
  // stage features[row0..row0+31, t, :] as swizzled bf16 [32][128]
  #pragma unroll
  for (int i = 0; i < 2; ++i){
    int cid = tid + i*NTHR;        // 0..1023
    int r   = cid >> 5;            // 0..31
    int c4  = cid & 31;            // float4 chunk
    const float4* fp = (const float4*)(feat + (size_t)(row0 + r)*(TSTEPS*FDIM) + (size_t)t*FDIM) + c4;
    float4 v = *fp;
    uint2 pk;
    pk.x = (unsigned)f2bf(v.x) | ((unsigned)f2bf(v.y) << 16);
    pk.y = (unsigned)f2bf(v.z) | ((unsigned)f2bf(v.w) << 16);
    int byte = r*256 + ((c4*8) ^ ((r & 7) << 4));
    *(uint2*)(sm_x + byte) = pk;
  }
}

#define GROUP_RZ(a0,a1,a2,a3,b0,b1) \
  arz[0][0]=MFMA(a0,b0,arz[0][0]); arz[0][1]=MFMA(a0,b1,arz[0][1]); \
  arz[1][0]=MFMA(a1,b0,arz[1][0]); arz[1][1]=MFMA(a1,b1,arz[1][1]); \
  arz[2][0]=MFMA(a2,b0,arz[2][0]); arz[2][1]=MFMA(a2,b1,arz[2][1]); \
  arz[3][0]=MFMA(a3,b0,arz[3][0]); arz[3][1]=MFMA(a3,b1,arz[3][1]);

// ---------------- main fused kernel ----------------
__global__ __launch_bounds__(NTHR, 2)
void gru_fused(const float* __restrict__ feat,
               const unsigned short* __restrict__ warr,
               const float* __restrict__ b_ih, const float* __restrict__ b_hh,
               const float* __restrict__ w_pi, const float* __restrict__ b_pi,
               const float* __restrict__ w_vf, const float* __restrict__ b_vf,
               float* __restrict__ out){
  __shared__ __align__(16) unsigned char sm_h[MROWS*512];  // 16KB bf16 [32][256] swizzled
  __shared__ __align__(16) unsigned char sm_x[MROWS*256];  // 8KB  bf16 [32][128] swizzled
  __shared__ __align__(16) float bias_sm[1024];            // 4KB: [0,512)=b_ih+b_hh (r,z),
                                                           // [512,768)=b_ih n, [768,1024)=b_hh n

  const int tid  = threadIdx.x;
  const int wv   = tid >> 6;           // wave 0..7 -> owns h-cols [32wv, 32wv+32)
  const int lane = tid & 63;
  const int lo   = lane & 15, hi = lane >> 4;
  const int row0 = blockIdx.x * MROWS;
  const int hc   = wv * 32;

  const unsigned short* wl = warr + lane*8;
  const int gfr = 2*wv, gfz = 16 + 2*wv, gfn = 32 + 2*wv;

  // ---- one-time: bias -> LDS
  {
    int c = tid;                               // 0..511
    bias_sm[c] = b_ih[c] + b_hh[c];
    if (c < 256){
      bias_sm[512 + c] = b_ih[512 + c];        // xn bias
      bias_sm[768 + c] = b_hh[512 + c];        // hn bias
    }
  }

  // ---- one-time: w_hh kf 0..5 -> registers (144 VGPRs/wave)
  short8 wreg[6][6];
  {
    const int gfs[6] = {gfr, gfr+1, gfz, gfz+1, gfn, gfn+1};
    #pragma unroll
    for (int g = 0; g < 6; ++g)
      #pragma unroll
      for (int kf = 0; kf < 6; ++kf)
        wreg[kf][g] = *(const short8*)(wl + gfs[g]*6144 + kf*512);
  }

  float hold[2][2][4];   // fp32 h state: [bnf][mfh][j]
  #pragma unroll
  for (int b = 0; b < 2; ++b)
    #pragma unroll
    for (int m = 0; m < 2; ++m)
      #pragma unroll
      for (int j = 0; j < 4; ++j) hold[b][m][j] = 0.f;

  // zero h LDS, stage x[0]
  #pragma unroll
  for (int i = 0; i < 2; ++i) ((int4*)sm_h)[tid + i*NTHR] = make_int4(0,0,0,0);
  stage_x(feat, sm_x, row0, tid, 0);
  __syncthreads();

  for (int t = 0; t < TSTEPS; ++t){
    // acc init from LDS biases (b128 reads, broadcast over lo / shared over b)
    floatx4 arz[4][2], axn[2][2], ahn[2][2];
    #pragma unroll
    for (int m = 0; m < 2; ++m){
      floatx4 br = *(const floatx4*)(bias_sm +        hc + 16*m + 4*hi);
      floatx4 bz = *(const floatx4*)(bias_sm + 256 +  hc + 16*m + 4*hi);
      floatx4 bx = *(const floatx4*)(bias_sm + 512 +  hc + 16*m + 4*hi);
      floatx4 bh = *(const floatx4*)(bias_sm + 768 +  hc + 16*m + 4*hi);
      arz[m][0]   = br; arz[m][1]   = br;
      arz[2+m][0] = bz; arz[2+m][1] = bz;
      axn[m][0]   = bx; axn[m][1]   = bx;
      ahn[m][0]   = bh; ahn[m][1]   = bh;
    }

    // h-part kf 0..5: A from registers
    #pragma unroll
    for (int kf = 0; kf < 6; ++kf){
      short8 b0 = ldsH(sm_h, lo,      kf*64 + hi*16);
      short8 b1 = ldsH(sm_h, 16 + lo, kf*64 + hi*16);
      GROUP_RZ(wreg[kf][0], wreg[kf][1], wreg[kf][2], wreg[kf][3], b0, b1);
      ahn[0][0] = MFMA(wreg[kf][4], b0, ahn[0][0]); ahn[0][1] = MFMA(wreg[kf][4], b1, ahn[0][1]);
      ahn[1][0] = MFMA(wreg[kf][5], b0, ahn[1][0]); ahn[1][1] = MFMA(wreg[kf][5], b1, ahn[1][1]);
    }
    // h-part kf 6,7: A streamed from global (L2-resident: 96KB/step/block)
    #pragma unroll
    for (int kf = 6; kf < 8; ++kf){
      short8 b0 = ldsH(sm_h, lo,      kf*64 + hi*16);
      short8 b1 = ldsH(sm_h, 16 + lo, kf*64 + hi*16);
      const int o = kf*512;
      short8 a0 = *(const short8*)(wl + gfr*6144     + o);
      short8 a1 = *(const short8*)(wl + (gfr+1)*6144 + o);
      short8 a2 = *(const short8*)(wl + gfz*6144     + o);
      short8 a3 = *(const short8*)(wl + (gfz+1)*6144 + o);
      short8 a4 = *(const short8*)(wl + gfn*6144     + o);
      short8 a5 = *(const short8*)(wl + (gfn+1)*6144 + o);
      GROUP_RZ(a0, a1, a2, a3, b0, b1);
      ahn[0][0] = MFMA(a4,b0,ahn[0][0]); ahn[0][1] = MFMA(a4,b1,ahn[0][1]);
      ahn[1][0] = MFMA(a5,b0,ahn[1][0]); ahn[1][1] = MFMA(a5,b1,ahn[1][1]);
    }
    // x-part kf 8..11: A streamed from global (192KB/step/block, L2-resident)
    #pragma unroll
    for (int kx = 0; kx < 4; ++kx){
      short8 b0 = ldsX(sm_x, lo,      kx*64 + hi*16);
      short8 b1 = ldsX(sm_x, 16 + lo, kx*64 + hi*16);
      const int o = (8 + kx)*512;
      short8 a0 = *(const short8*)(wl + gfr*6144     + o);
      short8 a1 = *(const short8*)(wl + (gfr+1)*6144 + o);
      short8 a2 = *(const short8*)(wl + gfz*6144     + o);
      short8 a3 = *(const short8*)(wl + (gfz+1)*6144 + o);
      short8 a4 = *(const short8*)(wl + gfn*6144     + o);
      short8 a5 = *(const short8*)(wl + (gfn+1)*6144 + o);
      GROUP_RZ(a0, a1, a2, a3, b0, b1);
      axn[0][0] = MFMA(a4,b0,axn[0][0]); axn[0][1] = MFMA(a4,b1,axn[0][1]);
      axn[1][0] = MFMA(a5,b0,axn[1][0]); axn[1][1] = MFMA(a5,b1,axn[1][1]);
    }
    __syncthreads();   // all reads of sm_h / sm_x done

    // lane-local gate math + h update; write new h (bf16, swizzled, 8B packed)
    #pragma unroll
    for (int b = 0; b < 2; ++b){
      int rowb = 16*b + lo;
      #pragma unroll
      for (int m = 0; m < 2; ++m){
        unsigned q[4];
        #pragma unroll
        for (int j = 0; j < 4; ++j){
          float r  = sigm(arz[m][b][j]);
          float z  = sigm(arz[2+m][b][j]);
          float n  = tanh_f(axn[m][b][j] + r*ahn[m][b][j]);
          float hv = (1.f - z)*n + z*hold[b][m][j];
          hold[b][m][j] = hv;
          q[j] = f2bf(hv);
        }
        uint2 pk; pk.x = q[0] | (q[1] << 16); pk.y = q[2] | (q[3] << 16);
        int cb   = (hc + 16*m + 4*hi) * 2;
        int byte = rowb*512 + (cb ^ ((rowb & 7) << 4));
        *(uint2*)(sm_h + byte) = pk;
      }
    }
    if (t + 1 < TSTEPS) stage_x(feat, sm_x, row0, tid, t + 1);
    __syncthreads();   // h[t+1], x[t+1] visible
  }

  // ---- heads: out = leaky(h_last); write bf16 to sm_h; then pi/vf = leaky(out@W^T+b)
  #pragma unroll
  for (int b = 0; b < 2; ++b){
    int rowb = 16*b + lo;
    #pragma unroll
    for (int m = 0; m < 2; ++m){
      unsigned q[4];
      #pragma unroll
      for (int j = 0; j < 4; ++j){
        float v = hold[b][m][j];
        v = (v >= 0.f) ? v : 0.01f*v;
        q[j] = f2bf(v);
      }
      uint2 pk; pk.x = q[0] | (q[1] << 16); pk.y = q[2] | (q[3] << 16);
      int cb   = (hc + 16*m + 4*hi) * 2;
      int byte = rowb*512 + (cb ^ ((rowb & 7) << 4));
      *(uint2*)(sm_h + byte) = pk;
    }
  }
  __syncthreads();

  const int head = wv >> 2;            // 0 = pi, 1 = vf
  const int mfo  = wv & 3;             // outdim frag
  const float* wh = head ? w_vf : w_pi;
  const float* bh = head ? b_vf : b_pi;
  floatx4 acc0 = {0.f,0.f,0.f,0.f}, acc1 = {0.f,0.f,0.f,0.f};
  #pragma unroll
  for (int kf = 0; kf < 8; ++kf){
    short8 b0 = ldsH(sm_h, lo,      kf*64 + hi*16);
    short8 b1 = ldsH(sm_h, 16 + lo, kf*64 + hi*16);
    const float* ap = wh + (size_t)(16*mfo + lo)*HDIM + 32*kf + 8*hi;
    float4 av0 = *(const float4*)ap;
    float4 av1 = *(const float4*)(ap + 4);
    short8 a;
    a[0]=(short)f2bf(av0.x); a[1]=(short)f2bf(av0.y); a[2]=(short)f2bf(av0.z); a[3]=(short)f2bf(av0.w);
    a[4]=(short)f2bf(av1.x); a[5]=(short)f2bf(av1.y); a[6]=(short)f2bf(av1.z); a[7]=(short)f2bf(av1.w);
    acc0 = MFMA(a, b0, acc0);
    acc1 = MFMA(a, b1, acc1);
  }
  const size_t outoff = (size_t)head * ((size_t)BATCH * ODIM);
  #pragma unroll
  for (int b = 0; b < 2; ++b){
    floatx4 ac = b ? acc1 : acc0;
    int grow = row0 + 16*b + lo;
    #pragma unroll
    for (int j = 0; j < 4; ++j){
      int od = 16*mfo + 4*hi + j;
      float v = ac[j] + bh[od];
      v = (v >= 0.f) ? v : 0.01f*v;
      out[outoff + (size_t)grow*ODIM + od] = v;
    }
  }
}

extern "C" void kernel_launch(void* const* d_in, const int* in_sizes, int n_in,
                              void* d_out, int out_size, void* d_ws, size_t ws_size,
                              hipStream_t stream){
  const float* feat = (const float*)d_in[0];
  const float* w_ih = (const float*)d_in[1];
  const float* w_hh = (const float*)d_in[2];
  const float* b_ih = (const float*)d_in[3];
  const float* b_hh = (const float*)d_in[4];
  const float* w_pi = (const float*)d_in[5];
  const float* b_pi = (const float*)d_in[6];
  const float* w_vf = (const float*)d_in[7];
  const float* b_vf = (const float*)d_in[8];
  unsigned short* warr = (unsigned short*)d_ws;   // 48*12*64*8 bf16 = 589824 B

  prep_weights<<<144, 256, 0, stream>>>(w_ih, w_hh, warr);
  gru_fused<<<NBLK, NTHR, 0, stream>>>(feat, warr, b_ih, b_hh,
                                       w_pi, b_pi, w_vf, b_vf, (float*)d_out);
}